// Round 4
// baseline (240.352 us; speedup 1.0000x reference)
//
#include <hip/hip_runtime.h>

// INT8-style BERT embeddings + approx LayerNorm, MI355X (gfx950).
// H=768 = 3 groups/lane * 64 lanes * 4 ints (int4 vector loads).
// One wave per token-stream; shuffle reductions only, no LDS/barriers.
// R4: persistent waves (4 tokens/wave), ids preloaded, double-buffered
//     row loads (software pipeline) to break the id->row->compute serial
//     chain; ln params loaded once per wave. Falsifies latency-bound
//     hypothesis: if neutral, kernel is bandwidth-bound at mandatory
//     traffic (~164 MB) and bench is harness-dominated.

constexpr int H_DIM = 768;
constexpr int TPB   = 256;          // 4 waves/block
constexpr int WPB   = TPB / 64;
constexpr int NBLK  = 2048;         // 8 blocks/CU -> 8192 waves persistent

typedef float nfloat4 __attribute__((ext_vector_type(4)));

struct RowBuf { int4 w[3], p[3], t[3]; };

__device__ __forceinline__ void issue_rows(
    RowBuf& b, int wid, int s, int ty, int lane,
    const int* __restrict__ word_table,
    const int* __restrict__ pos_table,
    const int* __restrict__ type_table)
{
    const int4* __restrict__ wr = (const int4*)(word_table + (size_t)wid * H_DIM);
    const int4* __restrict__ pr = (const int4*)(pos_table  + (size_t)s   * H_DIM);
    const int4* __restrict__ tr = (const int4*)(type_table + (size_t)ty  * H_DIM);
#pragma unroll
    for (int j = 0; j < 3; ++j) {
        const int g = j * 64 + lane;
        b.w[j] = wr[g];
        b.p[j] = pr[g];
        b.t[j] = tr[g];
    }
}

__device__ __forceinline__ void finish_token(
    const RowBuf& b, int token, int lane,
    float ws, float ps, float ts,
    const float4 lw[3], const float4 lb[3],
    float* __restrict__ out)
{
    float e[3][4];
    float sum = 0.f, sq = 0.f;
#pragma unroll
    for (int j = 0; j < 3; ++j) {
        e[j][0] = (float)b.w[j].x * ws + (float)b.p[j].x * ps + (float)b.t[j].x * ts;
        e[j][1] = (float)b.w[j].y * ws + (float)b.p[j].y * ps + (float)b.t[j].y * ts;
        e[j][2] = (float)b.w[j].z * ws + (float)b.p[j].z * ps + (float)b.t[j].z * ts;
        e[j][3] = (float)b.w[j].w * ws + (float)b.p[j].w * ps + (float)b.t[j].w * ts;
#pragma unroll
        for (int k = 0; k < 4; ++k) { sum += e[j][k]; sq += e[j][k] * e[j][k]; }
    }
    // interleaved 6-level butterfly (both accumulators per level)
#pragma unroll
    for (int off = 1; off < 64; off <<= 1) {
        sum += __shfl_xor(sum, off);
        sq  += __shfl_xor(sq, off);
    }
    const float mean = sum * (1.0f / (float)H_DIM);
    float var = sq * (1.0f / (float)H_DIM) - mean * mean;
    var = var < 0.f ? 0.f : var;
    // 8-iter NR converges to fp32 sqrt for realistic var; sqrtf matches ~1 ULP
    const float inv = 1.0f / (sqrtf(var) + 1e-12f);

    nfloat4* __restrict__ orow = (nfloat4*)(out + (size_t)token * H_DIM);
#pragma unroll
    for (int j = 0; j < 3; ++j) {
        nfloat4 o;
        o.x = lw[j].x * ((e[j][0] - mean) * inv) + lb[j].x;
        o.y = lw[j].y * ((e[j][1] - mean) * inv) + lb[j].y;
        o.z = lw[j].z * ((e[j][2] - mean) * inv) + lb[j].z;
        o.w = lw[j].w * ((e[j][3] - mean) * inv) + lb[j].w;
        __builtin_nontemporal_store(o, &orow[j * 64 + lane]);
    }
}

__global__ __launch_bounds__(TPB, 4) void bert_emb_kernel(
    const int* __restrict__ input_ids,
    const int* __restrict__ token_type_ids,
    const int* __restrict__ word_table,
    const float* __restrict__ word_scale,
    const int* __restrict__ pos_table,
    const float* __restrict__ pos_scale,
    const int* __restrict__ type_table,
    const float* __restrict__ type_scale,
    const float* __restrict__ ln_w,
    const float* __restrict__ ln_b,
    float* __restrict__ out,
    int n_tokens, int S)
{
    const int wave  = threadIdx.x >> 6;
    const int lane  = threadIdx.x & 63;
    const int gwave = blockIdx.x * WPB + wave;
    const int nwave = gridDim.x * WPB;

    int t = gwave;
    if (t >= n_tokens) return;

    const float ws = word_scale[0];
    const float ps = pos_scale[0];
    const float ts = type_scale[0];

    // ln params: identical for every token this wave handles — load once
    float4 lw[3], lb[3];
#pragma unroll
    for (int j = 0; j < 3; ++j) {
        lw[j] = ((const float4*)ln_w)[j * 64 + lane];
        lb[j] = ((const float4*)ln_b)[j * 64 + lane];
    }

    RowBuf A, B;
    // prologue: ids + rows for first token
    issue_rows(A, input_ids[t], t % S, token_type_ids[t], lane,
               word_table, pos_table, type_table);

    // 2x-unrolled pipeline so buffer names are compile-time (no reg-array
    // runtime indexing -> no scratch spill)
    for (;;) {
        int tn = t + nwave;
        if (tn < n_tokens)
            issue_rows(B, input_ids[tn], tn % S, token_type_ids[tn], lane,
                       word_table, pos_table, type_table);
        finish_token(A, t, lane, ws, ps, ts, lw, lb, out);
        if (tn >= n_tokens) return;
        t = tn;

        tn = t + nwave;
        if (tn < n_tokens)
            issue_rows(A, input_ids[tn], tn % S, token_type_ids[tn], lane,
                       word_table, pos_table, type_table);
        finish_token(B, t, lane, ws, ps, ts, lw, lb, out);
        if (tn >= n_tokens) return;
        t = tn;
    }
}

extern "C" void kernel_launch(void* const* d_in, const int* in_sizes, int n_in,
                              void* d_out, int out_size, void* d_ws, size_t ws_size,
                              hipStream_t stream) {
    const int*   input_ids      = (const int*)d_in[0];
    const int*   token_type_ids = (const int*)d_in[1];
    const int*   word_table     = (const int*)d_in[2];
    const float* word_scale     = (const float*)d_in[3];
    const int*   pos_table      = (const int*)d_in[4];
    const float* pos_scale      = (const float*)d_in[5];
    const int*   type_table     = (const int*)d_in[6];
    const float* type_scale     = (const float*)d_in[7];
    const float* ln_w           = (const float*)d_in[8];
    const float* ln_b           = (const float*)d_in[9];
    float* out = (float*)d_out;

    const int n_tokens = in_sizes[0];        // B*S
    const int S = in_sizes[4] / H_DIM;       // pos_table rows

    const int waves_needed  = (n_tokens + 0) ;  // one token per wave min
    const int blocks_needed = (n_tokens + WPB - 1) / WPB;
    const int blocks = blocks_needed < NBLK ? blocks_needed : NBLK;
    (void)waves_needed;

    bert_emb_kernel<<<blocks, TPB, 0, stream>>>(
        input_ids, token_type_ids, word_table, word_scale,
        pos_table, pos_scale, type_table, type_scale,
        ln_w, ln_b, out, n_tokens, S);
}

// Round 5
// 197.878 us; speedup vs baseline: 1.2146x; 1.2146x over previous
//
#include <hip/hip_runtime.h>

// INT8-style BERT embeddings + approx LayerNorm, MI355X (gfx950).
// H=768 = 3 groups/lane * 64 lanes * 4 ints (int4 vector loads).
// One wave handles TWO ADJACENT tokens, straight-line (no loop): all 18
// row loads issued before any use -> 2x per-wave MLP, one 8B id load,
// shared pos/L2 lines, 6KB contiguous output per wave.
// R5 post-mortems baked in:
//  - R4 persistent loop: compiler targeted 64-VGPR tier and sank the
//    prefetch loads -> serialized. Fix: straight-line code +
//    __launch_bounds__(256,2) so both row buffers stay live.
//  - nt stores: WRITE_SIZE showed exactly 2x (16B/lane EA requests
//    counted at 32B) -> use regular stores, L2 coalesces full lines.
//  - sqrtf == reference's 8-iter NR (converged, ~1 ULP).

constexpr int H_DIM = 768;
constexpr int TPB   = 256;          // 4 waves/block
constexpr int WPB   = TPB / 64;

struct RowBuf { int4 w[3], p[3], t[3]; };

__device__ __forceinline__ void issue_rows(
    RowBuf& b, int wid, int s, int ty, int lane,
    const int* __restrict__ word_table,
    const int* __restrict__ pos_table,
    const int* __restrict__ type_table)
{
    const int4* __restrict__ wr = (const int4*)(word_table + (size_t)wid * H_DIM);
    const int4* __restrict__ pr = (const int4*)(pos_table  + (size_t)s   * H_DIM);
    const int4* __restrict__ tr = (const int4*)(type_table + (size_t)ty  * H_DIM);
#pragma unroll
    for (int j = 0; j < 3; ++j) {
        const int g = j * 64 + lane;
        b.w[j] = wr[g];
        b.p[j] = pr[g];
        b.t[j] = tr[g];
    }
}

__device__ __forceinline__ void finish_token(
    const RowBuf& b, int token, int lane,
    float ws, float ps, float ts,
    const float4 lw[3], const float4 lb[3],
    float* __restrict__ out)
{
    float e[3][4];
    float sum = 0.f, sq = 0.f;
#pragma unroll
    for (int j = 0; j < 3; ++j) {
        e[j][0] = (float)b.w[j].x * ws + (float)b.p[j].x * ps + (float)b.t[j].x * ts;
        e[j][1] = (float)b.w[j].y * ws + (float)b.p[j].y * ps + (float)b.t[j].y * ts;
        e[j][2] = (float)b.w[j].z * ws + (float)b.p[j].z * ps + (float)b.t[j].z * ts;
        e[j][3] = (float)b.w[j].w * ws + (float)b.p[j].w * ps + (float)b.t[j].w * ts;
#pragma unroll
        for (int k = 0; k < 4; ++k) { sum += e[j][k]; sq += e[j][k] * e[j][k]; }
    }
    // interleaved 6-level butterfly (both accumulators per level)
#pragma unroll
    for (int off = 1; off < 64; off <<= 1) {
        sum += __shfl_xor(sum, off);
        sq  += __shfl_xor(sq, off);
    }
    const float mean = sum * (1.0f / (float)H_DIM);
    float var = sq * (1.0f / (float)H_DIM) - mean * mean;
    var = var < 0.f ? 0.f : var;
    const float inv = 1.0f / (sqrtf(var) + 1e-12f);

    float4* __restrict__ orow = (float4*)(out + (size_t)token * H_DIM);
#pragma unroll
    for (int j = 0; j < 3; ++j) {
        float4 o;
        o.x = lw[j].x * ((e[j][0] - mean) * inv) + lb[j].x;
        o.y = lw[j].y * ((e[j][1] - mean) * inv) + lb[j].y;
        o.z = lw[j].z * ((e[j][2] - mean) * inv) + lb[j].z;
        o.w = lw[j].w * ((e[j][3] - mean) * inv) + lb[j].w;
        orow[j * 64 + lane] = o;
    }
}

__global__ __launch_bounds__(TPB, 2) void bert_emb_kernel(
    const int* __restrict__ input_ids,
    const int* __restrict__ token_type_ids,
    const int* __restrict__ word_table,
    const float* __restrict__ word_scale,
    const int* __restrict__ pos_table,
    const float* __restrict__ pos_scale,
    const int* __restrict__ type_table,
    const float* __restrict__ type_scale,
    const float* __restrict__ ln_w,
    const float* __restrict__ ln_b,
    float* __restrict__ out,
    int n_tokens, int S)
{
    const int wave  = threadIdx.x >> 6;
    const int lane  = threadIdx.x & 63;
    const int gwave = blockIdx.x * WPB + wave;

    const int t0 = gwave * 2;
    if (t0 >= n_tokens) return;
    const int t1 = t0 + 1;
    const bool has1 = t1 < n_tokens;

    // one 8B load covers both tokens' ids (t0 even -> aligned)
    const int2 ids = ((const int2*)input_ids)[gwave];
    const int2 tts = ((const int2*)token_type_ids)[gwave];

    const int s0 = t0 % S;
    const int s1 = (s0 + 1 == S) ? 0 : s0 + 1;   // avoid second modulo

    const float ws = word_scale[0];
    const float ps = pos_scale[0];
    const float ts = type_scale[0];

    // issue ALL row loads before any use: 18 loads in flight per wave
    RowBuf A, B;
    issue_rows(A, ids.x, s0, tts.x, lane, word_table, pos_table, type_table);
    if (has1)
        issue_rows(B, ids.y, s1, tts.y, lane, word_table, pos_table, type_table);

    float4 lw[3], lb[3];
#pragma unroll
    for (int j = 0; j < 3; ++j) {
        lw[j] = ((const float4*)ln_w)[j * 64 + lane];
        lb[j] = ((const float4*)ln_b)[j * 64 + lane];
    }

    finish_token(A, t0, lane, ws, ps, ts, lw, lb, out);
    if (has1)
        finish_token(B, t1, lane, ws, ps, ts, lw, lb, out);
}

extern "C" void kernel_launch(void* const* d_in, const int* in_sizes, int n_in,
                              void* d_out, int out_size, void* d_ws, size_t ws_size,
                              hipStream_t stream) {
    const int*   input_ids      = (const int*)d_in[0];
    const int*   token_type_ids = (const int*)d_in[1];
    const int*   word_table     = (const int*)d_in[2];
    const float* word_scale     = (const float*)d_in[3];
    const int*   pos_table      = (const int*)d_in[4];
    const float* pos_scale      = (const float*)d_in[5];
    const int*   type_table     = (const int*)d_in[6];
    const float* type_scale     = (const float*)d_in[7];
    const float* ln_w           = (const float*)d_in[8];
    const float* ln_b           = (const float*)d_in[9];
    float* out = (float*)d_out;

    const int n_tokens = in_sizes[0];        // B*S
    const int S = in_sizes[4] / H_DIM;       // pos_table rows

    const int nwaves = (n_tokens + 1) / 2;   // 2 tokens per wave
    const int blocks = (nwaves + WPB - 1) / WPB;
    bert_emb_kernel<<<blocks, TPB, 0, stream>>>(
        input_ids, token_type_ids, word_table, word_scale,
        pos_table, pos_scale, type_table, type_scale,
        ln_w, ln_b, out, n_tokens, S);
}